// Round 1
// baseline (1185.920 us; speedup 1.0000x reference)
//
#include <hip/hip_runtime.h>
#include <hip/hip_bf16.h>
#include <math.h>

#define Bb 4
#define Tt 512
#define Ss 512
#define Hh 1024
#define Vv 32000
#define Dd 513
#define OUTW (Vv + 2*Dd)    // 33026
#define ROWS (Bb*Tt)        // 2048

typedef float f32x4 __attribute__((ext_vector_type(4)));
typedef __bf16 bf16x8 __attribute__((ext_vector_type(8)));

// ---------- helpers ----------
static __device__ __forceinline__ unsigned short f2bf_rne(float f) {
    union { float f; unsigned int u; } a; a.f = f;
    unsigned int u = a.u;
    unsigned int rounding = 0x7FFFu + ((u >> 16) & 1u);
    u += rounding;
    return (unsigned short)(u >> 16);
}

// ---------- 1. f32 -> bf16 conversion ----------
__global__ __launch_bounds__(256) void f32_to_bf16_kernel(const float* __restrict__ in,
                                                          unsigned short* __restrict__ outp,
                                                          size_t n) {
    size_t i = ((size_t)blockIdx.x * blockDim.x + threadIdx.x) * 4;
    if (i + 3 < n) {
        float4 v = *reinterpret_cast<const float4*>(in + i);
        ushort4 r;
        r.x = f2bf_rne(v.x); r.y = f2bf_rne(v.y);
        r.z = f2bf_rne(v.z); r.w = f2bf_rne(v.w);
        *reinterpret_cast<ushort4*>(outp + i) = r;
    }
}

// ---------- 2. switch softmax (f64) ----------
__global__ __launch_bounds__(64) void switch_kernel(const float* __restrict__ hiddens,
                                                    const float* __restrict__ Wsw,
                                                    const float* __restrict__ bsw,
                                                    double* __restrict__ p) {
    int row = blockIdx.x;
    int lane = threadIdx.x;
    const float* h = hiddens + (size_t)row * Hh;
    double acc0 = 0.0, acc1 = 0.0, acc2 = 0.0;
    for (int i = lane; i < Hh; i += 64) {
        double hv = (double)h[i];
        acc0 += hv * (double)Wsw[i];
        acc1 += hv * (double)Wsw[Hh + i];
        acc2 += hv * (double)Wsw[2*Hh + i];
    }
    for (int off = 32; off > 0; off >>= 1) {
        acc0 += __shfl_down(acc0, off);
        acc1 += __shfl_down(acc1, off);
        acc2 += __shfl_down(acc2, off);
    }
    if (lane == 0) {
        double l0 = acc0 + (double)bsw[0];
        double l1 = acc1 + (double)bsw[1];
        double l2 = acc2 + (double)bsw[2];
        double mx = fmax(l0, fmax(l1, l2));
        double e0 = exp(l0 - mx), e1 = exp(l1 - mx), e2 = exp(l2 - mx);
        double s = e0 + e1 + e2;
        p[row*3 + 0] = e0 / s;
        p[row*3 + 1] = e1 / s;
        p[row*3 + 2] = e2 / s;
    }
}

// ---------- 3. bf16 MFMA GEMM: scores -> d_out vocab slice ----------
#define GLOAD_LDS16(g, l) __builtin_amdgcn_global_load_lds( \
    (__attribute__((address_space(1))) void*)(g), \
    (__attribute__((address_space(3))) void*)(l), 16, 0, 0)

__global__ __launch_bounds__(256) void gemm_scores(const unsigned short* __restrict__ A,  // 2048x1024 bf16
                                                   const unsigned short* __restrict__ W,  // 32000x1024 bf16
                                                   const float* __restrict__ bias,        // 32000
                                                   float* __restrict__ out) {             // 2048 x OUTW
    __shared__ __align__(16) unsigned short As[128 * 32];
    __shared__ __align__(16) unsigned short Bs[128 * 32];
    int tid  = threadIdx.x;
    int lane = tid & 63;
    int w    = tid >> 6;
    int wr   = w >> 1, wc = w & 1;
    int m0 = blockIdx.x * 128;
    int n0 = blockIdx.y * 128;

    f32x4 acc[4][4] = {};

    const unsigned short* Abase = A + (size_t)m0 * Hh;
    const unsigned short* Wbase = W + (size_t)n0 * Hh;

    for (int kt = 0; kt < Hh; kt += 32) {
        #pragma unroll
        for (int gg = 0; gg < 2; ++gg) {
            int g = tid + gg * 256;       // 0..511
            int row = g >> 2, seg = g & 3;
            const unsigned short* ga = Abase + (size_t)row * Hh + kt + seg * 8;
            const unsigned short* gb = Wbase + (size_t)row * Hh + kt + seg * 8;
            GLOAD_LDS16(ga, &As[g * 8]);
            GLOAD_LDS16(gb, &Bs[g * 8]);
        }
        __syncthreads();

        bf16x8 af[4], bf[4];
        int r = lane & 15, k8 = (lane >> 4) * 8;
        #pragma unroll
        for (int i = 0; i < 4; ++i) {
            af[i] = *reinterpret_cast<const bf16x8*>(&As[(wr*64 + i*16 + r) * 32 + k8]);
            bf[i] = *reinterpret_cast<const bf16x8*>(&Bs[(wc*64 + i*16 + r) * 32 + k8]);
        }
        #pragma unroll
        for (int mi = 0; mi < 4; ++mi)
            #pragma unroll
            for (int ni = 0; ni < 4; ++ni)
                acc[mi][ni] = __builtin_amdgcn_mfma_f32_16x16x32_bf16(af[mi], bf[ni], acc[mi][ni], 0, 0, 0);
        __syncthreads();
    }

    // epilogue: add bias, col 0 -> -inf, store to out (stride OUTW)
    #pragma unroll
    for (int mi = 0; mi < 4; ++mi) {
        #pragma unroll
        for (int ni = 0; ni < 4; ++ni) {
            int col = n0 + wc*64 + ni*16 + (lane & 15);
            float bv = bias[col];
            #pragma unroll
            for (int rg = 0; rg < 4; ++rg) {
                int row = m0 + wr*64 + mi*16 + (lane >> 4) * 4 + rg;
                float v = acc[mi][ni][rg] + bv;
                if (col == 0) v = -INFINITY;
                out[(size_t)row * OUTW + col] = v;
            }
        }
    }
}

// ---------- 4. per-row softmax stats + vocab argmax ----------
__global__ __launch_bounds__(256) void softmax_stats(const float* __restrict__ out,
                                                     float* __restrict__ rowmax,
                                                     float* __restrict__ rowsum,
                                                     int* __restrict__ rowidx) {
    int row = blockIdx.x, tid = threadIdx.x;
    const float* x = out + (size_t)row * OUTW;
    float m = -1e30f, s = 0.0f; int idx = 0;
    for (int v = tid; v < Vv; v += 256) {
        float val = x[v];
        if (val > m) {
            s = s * expf(m - val);
            m = val; idx = v;
            s += 1.0f;
        } else {
            s += expf(val - m);   // val=-inf -> expf(-inf)=0
        }
    }
    __shared__ float lm[256], ls[256];
    __shared__ int   li[256];
    lm[tid] = m; ls[tid] = s; li[tid] = idx;
    __syncthreads();
    if (tid == 0) {
        float M = -1e30f, S = 0.0f; int I = 0x7fffffff;
        for (int t = 0; t < 256; ++t) {
            float mt = lm[t], st = ls[t];
            float newM = fmaxf(M, mt);
            S = S * expf(M - newM) + st * expf(mt - newM);
            if (mt > M) { I = li[t]; M = newM; }
            else if (mt == M && li[t] < I) { I = li[t]; }
        }
        rowmax[row] = M; rowsum[row] = S; rowidx[row] = I;
    }
}

// ---------- 5. in-place vocab prob write ----------
__global__ __launch_bounds__(256) void vocab_write(float* __restrict__ out,
                                                   const float* __restrict__ rowmax,
                                                   const float* __restrict__ rowsum,
                                                   const double* __restrict__ p) {
    int row = blockIdx.y;
    int v = blockIdx.x * 256 + threadIdx.x;   // 125*256 = 32000 exact
    float* xr = out + (size_t)row * OUTW;
    float m = rowmax[row];
    float scale = (float)(p[row*3 + 2]) / rowsum[row];
    float val = (v == 0) ? 0.0f : expf(xr[v] - m) * scale;
    xr[v] = val;
}

// ---------- 6. copy einsums (f64 accumulate) ----------
__global__ __launch_bounds__(256) void copy_kernel(const float* __restrict__ attn,  // (B,512,512)
                                                   const int* __restrict__ map,     // (B,512,513)
                                                   const double* __restrict__ p, int pcomp,
                                                   float* __restrict__ out, int outoff) {
    __shared__ float attn_lds[16][512];
    int bidx = blockIdx.x;          // 128 blocks: 4 b * 32 chunks
    int b = bidx >> 5;
    int tc = bidx & 31;
    int t0 = tc * 16;
    int tid = threadIdx.x;
    size_t abase = ((size_t)b * Tt + t0) * 512;
    for (int i = tid; i < 16 * 512; i += 256)
        attn_lds[i >> 9][i & 511] = attn[abase + i];
    __syncthreads();
    const int* mapb = map + (size_t)b * 512 * Dd;
    for (int dg = 0; dg < 3; ++dg) {
        int d = dg * 256 + tid;
        if (d >= Dd) continue;
        double acc[16];
        #pragma unroll
        for (int r = 0; r < 16; ++r) acc[r] = 0.0;
        for (int s = 0; s < 512; ++s) {
            double mv = (double)mapb[(size_t)s * Dd + d];
            #pragma unroll
            for (int r = 0; r < 16; ++r)
                acc[r] = fma((double)attn_lds[r][s], mv, acc[r]);
        }
        #pragma unroll
        for (int r = 0; r < 16; ++r) {
            int row = b * Tt + t0 + r;
            double pv = p[row*3 + pcomp];
            out[(size_t)row * OUTW + outoff + d] = (float)(acc[r] * pv);
        }
    }
}

// ---------- 7. predictions ----------
__global__ __launch_bounds__(256) void pred_kernel(const float* __restrict__ out,
                                                   const int* __restrict__ rowidx,
                                                   float* __restrict__ preds) {
    int row = blockIdx.x, tid = threadIdx.x;
    const float* xr = out + (size_t)row * OUTW;
    float bv = -1.0f; int bi = 0x7fffffff;
    for (int d = tid; d < 2 * Dd; d += 256) {
        if (d == Dd) continue;            // global index Vv+Dd = 32513 zeroed in _probs
        float v = xr[Vv + d];
        int gi = Vv + d;
        if (v > bv || (v == bv && gi < bi)) { bv = v; bi = gi; }
    }
    __shared__ float lv[256];
    __shared__ int   li[256];
    lv[tid] = bv; li[tid] = bi;
    __syncthreads();
    if (tid == 0) {
        int I = rowidx[row];
        float V = xr[I];                  // vocab candidate (scaled prob at vocab argmax)
        for (int t = 0; t < 256; ++t) {
            if (lv[t] > V || (lv[t] == V && li[t] < I)) { V = lv[t]; I = li[t]; }
        }
        preds[row] = (float)I;
    }
}

// ---------- launch ----------
extern "C" void kernel_launch(void* const* d_in, const int* in_sizes, int n_in,
                              void* d_out, int out_size, void* d_ws, size_t ws_size,
                              hipStream_t stream) {
    const float* hiddens  = (const float*)d_in[0];
    const float* src_attn = (const float*)d_in[1];
    const int*   src_map  = (const int*)  d_in[2];
    const float* tgt_attn = (const float*)d_in[3];
    const int*   tgt_map  = (const int*)  d_in[4];
    const float* W_vocab  = (const float*)d_in[5];
    const float* b_vocab  = (const float*)d_in[6];
    const float* W_switch = (const float*)d_in[7];
    const float* b_switch = (const float*)d_in[8];

    float* out = (float*)d_out;
    char* ws = (char*)d_ws;

    const size_t HBF_OFF  = 0;
    const size_t WBF_OFF  = HBF_OFF + (size_t)ROWS * Hh * 2;          // 4,194,304
    const size_t P_OFF    = WBF_OFF + (size_t)Vv * Hh * 2;            // +65,536,000
    const size_t RMAX_OFF = P_OFF + (size_t)ROWS * 3 * 8;
    const size_t RSUM_OFF = RMAX_OFF + (size_t)ROWS * 4;
    const size_t RIDX_OFF = RSUM_OFF + (size_t)ROWS * 4;

    unsigned short* hbf  = (unsigned short*)(ws + HBF_OFF);
    unsigned short* wbf  = (unsigned short*)(ws + WBF_OFF);
    double* pws          = (double*)(ws + P_OFF);
    float* rowmax        = (float*)(ws + RMAX_OFF);
    float* rowsum        = (float*)(ws + RSUM_OFF);
    int*   rowidx        = (int*)(ws + RIDX_OFF);

    float* preds = out + (size_t)ROWS * OUTW;

    // 1. bf16 conversions
    f32_to_bf16_kernel<<<(ROWS*Hh)/1024, 256, 0, stream>>>(hiddens, hbf, (size_t)ROWS*Hh);
    f32_to_bf16_kernel<<<((size_t)Vv*Hh)/1024, 256, 0, stream>>>(W_vocab, wbf, (size_t)Vv*Hh);

    // 2. switch softmax (f64)
    switch_kernel<<<ROWS, 64, 0, stream>>>(hiddens, W_switch, b_switch, pws);

    // 3. vocab GEMM -> raw scores into out vocab slice
    dim3 gg(ROWS/128, Vv/128);   // (16, 250)
    gemm_scores<<<gg, 256, 0, stream>>>(hbf, wbf, b_vocab, out);

    // 4. softmax stats
    softmax_stats<<<ROWS, 256, 0, stream>>>(out, rowmax, rowsum, rowidx);

    // 5. in-place vocab prob write
    vocab_write<<<dim3(Vv/256, ROWS), 256, 0, stream>>>(out, rowmax, rowsum, pws);

    // 6. copy einsums
    copy_kernel<<<128, 256, 0, stream>>>(src_attn, src_map, pws, 0, out, Vv);
    copy_kernel<<<128, 256, 0, stream>>>(tgt_attn, tgt_map, pws, 1, out, Vv + Dd);

    // 7. predictions
    pred_kernel<<<ROWS, 256, 0, stream>>>(out, rowidx, preds);
}

// Round 2
// 569.157 us; speedup vs baseline: 2.0836x; 2.0836x over previous
//
#include <hip/hip_runtime.h>
#include <hip/hip_bf16.h>
#include <math.h>

#define Bb 4
#define Tt 512
#define Ss 512
#define Hh 1024
#define Vv 32000
#define Dd 513
#define DP 640              // padded D for copy GEMM (5 x 128 tiles)
#define OUTW (Vv + 2*Dd)    // 33026
#define ROWS (Bb*Tt)        // 2048

typedef float f32x4 __attribute__((ext_vector_type(4)));
typedef __bf16 bf16x8 __attribute__((ext_vector_type(8)));

// ---------- helpers ----------
static __device__ __forceinline__ unsigned short f2bf_rne(float f) {
    union { float f; unsigned int u; } a; a.f = f;
    unsigned int u = a.u;
    unsigned int rounding = 0x7FFFu + ((u >> 16) & 1u);
    u += rounding;
    return (unsigned short)(u >> 16);
}
static __device__ __forceinline__ float bf2f(unsigned short h) {
    union { unsigned int u; float f; } a; a.u = ((unsigned int)h) << 16;
    return a.f;
}

// ---------- 1. f32 -> bf16 conversion ----------
__global__ __launch_bounds__(256) void f32_to_bf16_kernel(const float* __restrict__ in,
                                                          unsigned short* __restrict__ outp,
                                                          size_t n) {
    size_t i = ((size_t)blockIdx.x * blockDim.x + threadIdx.x) * 4;
    if (i + 3 < n) {
        float4 v = *reinterpret_cast<const float4*>(in + i);
        ushort4 r;
        r.x = f2bf_rne(v.x); r.y = f2bf_rne(v.y);
        r.z = f2bf_rne(v.z); r.w = f2bf_rne(v.w);
        *reinterpret_cast<ushort4*>(outp + i) = r;
    }
}

// ---------- 1b. attn -> hi/lo bf16 split ----------
__global__ __launch_bounds__(256) void split_attn_kernel(const float* __restrict__ in,
                                                         unsigned short* __restrict__ hi,
                                                         unsigned short* __restrict__ lo,
                                                         size_t n) {
    size_t i = ((size_t)blockIdx.x * blockDim.x + threadIdx.x) * 4;
    if (i + 3 < n) {
        float4 v = *reinterpret_cast<const float4*>(in + i);
        ushort4 h, l;
        h.x = f2bf_rne(v.x); l.x = f2bf_rne(v.x - bf2f(h.x));
        h.y = f2bf_rne(v.y); l.y = f2bf_rne(v.y - bf2f(h.y));
        h.z = f2bf_rne(v.z); l.z = f2bf_rne(v.z - bf2f(h.z));
        h.w = f2bf_rne(v.w); l.w = f2bf_rne(v.w - bf2f(h.w));
        *reinterpret_cast<ushort4*>(hi + i) = h;
        *reinterpret_cast<ushort4*>(lo + i) = l;
    }
}

// ---------- 1c. map transpose + bf16 convert: (B,S,513)i32 -> (B,640,512)bf16 ----------
__global__ __launch_bounds__(256) void map_transpose(const int* __restrict__ smap,
                                                     const int* __restrict__ tmap,
                                                     unsigned short* __restrict__ mt_s,
                                                     unsigned short* __restrict__ mt_t) {
    __shared__ float tile[32][33];
    int z = blockIdx.z; int b = z >> 1; int sel = z & 1;
    const int* mp = (sel ? tmap : smap) + (size_t)b * Ss * Dd;
    unsigned short* op = (sel ? mt_t : mt_s) + (size_t)b * DP * Ss;
    int d0 = blockIdx.x * 32, s0 = blockIdx.y * 32;
    int x = threadIdx.x & 31, y = threadIdx.x >> 5;
    #pragma unroll
    for (int r = 0; r < 4; ++r) {
        int s = s0 + y + r*8, d = d0 + x;
        float v = (d < Dd) ? (float)mp[(size_t)s * Dd + d] : 0.0f;
        tile[y + r*8][x] = v;
    }
    __syncthreads();
    #pragma unroll
    for (int r = 0; r < 4; ++r) {
        int dd = d0 + y + r*8, ss = s0 + x;
        op[(size_t)dd * Ss + ss] = f2bf_rne(tile[x][y + r*8]);
    }
}

// ---------- 2. switch softmax (f64) ----------
__global__ __launch_bounds__(64) void switch_kernel(const float* __restrict__ hiddens,
                                                    const float* __restrict__ Wsw,
                                                    const float* __restrict__ bsw,
                                                    double* __restrict__ p) {
    int row = blockIdx.x;
    int lane = threadIdx.x;
    const float* h = hiddens + (size_t)row * Hh;
    double acc0 = 0.0, acc1 = 0.0, acc2 = 0.0;
    for (int i = lane; i < Hh; i += 64) {
        double hv = (double)h[i];
        acc0 += hv * (double)Wsw[i];
        acc1 += hv * (double)Wsw[Hh + i];
        acc2 += hv * (double)Wsw[2*Hh + i];
    }
    for (int off = 32; off > 0; off >>= 1) {
        acc0 += __shfl_down(acc0, off);
        acc1 += __shfl_down(acc1, off);
        acc2 += __shfl_down(acc2, off);
    }
    if (lane == 0) {
        double l0 = acc0 + (double)bsw[0];
        double l1 = acc1 + (double)bsw[1];
        double l2 = acc2 + (double)bsw[2];
        double mx = fmax(l0, fmax(l1, l2));
        double e0 = exp(l0 - mx), e1 = exp(l1 - mx), e2 = exp(l2 - mx);
        double s = e0 + e1 + e2;
        p[row*3 + 0] = e0 / s;
        p[row*3 + 1] = e1 / s;
        p[row*3 + 2] = e2 / s;
    }
}

// ---------- 3. bf16 MFMA GEMM: scores -> d_out vocab slice ----------
#define GLOAD_LDS16(g, l) __builtin_amdgcn_global_load_lds( \
    (__attribute__((address_space(1))) void*)(g), \
    (__attribute__((address_space(3))) void*)(l), 16, 0, 0)

__global__ __launch_bounds__(256) void gemm_scores(const unsigned short* __restrict__ A,  // 2048x1024 bf16
                                                   const unsigned short* __restrict__ W,  // 32000x1024 bf16
                                                   const float* __restrict__ bias,        // 32000
                                                   float* __restrict__ out) {             // 2048 x OUTW
    __shared__ __align__(16) unsigned short As[128 * 32];
    __shared__ __align__(16) unsigned short Bs[128 * 32];
    int tid  = threadIdx.x;
    int lane = tid & 63;
    int w    = tid >> 6;
    int wr   = w >> 1, wc = w & 1;
    int m0 = blockIdx.x * 128;
    int n0 = blockIdx.y * 128;

    f32x4 acc[4][4] = {};

    const unsigned short* Abase = A + (size_t)m0 * Hh;
    const unsigned short* Wbase = W + (size_t)n0 * Hh;

    for (int kt = 0; kt < Hh; kt += 32) {
        #pragma unroll
        for (int gg = 0; gg < 2; ++gg) {
            int g = tid + gg * 256;       // 0..511
            int row = g >> 2, seg = g & 3;
            const unsigned short* ga = Abase + (size_t)row * Hh + kt + seg * 8;
            const unsigned short* gb = Wbase + (size_t)row * Hh + kt + seg * 8;
            GLOAD_LDS16(ga, &As[g * 8]);
            GLOAD_LDS16(gb, &Bs[g * 8]);
        }
        __syncthreads();

        bf16x8 af[4], bf[4];
        int r = lane & 15, k8 = (lane >> 4) * 8;
        #pragma unroll
        for (int i = 0; i < 4; ++i) {
            af[i] = *reinterpret_cast<const bf16x8*>(&As[(wr*64 + i*16 + r) * 32 + k8]);
            bf[i] = *reinterpret_cast<const bf16x8*>(&Bs[(wc*64 + i*16 + r) * 32 + k8]);
        }
        #pragma unroll
        for (int mi = 0; mi < 4; ++mi)
            #pragma unroll
            for (int ni = 0; ni < 4; ++ni)
                acc[mi][ni] = __builtin_amdgcn_mfma_f32_16x16x32_bf16(af[mi], bf[ni], acc[mi][ni], 0, 0, 0);
        __syncthreads();
    }

    #pragma unroll
    for (int mi = 0; mi < 4; ++mi) {
        #pragma unroll
        for (int ni = 0; ni < 4; ++ni) {
            int col = n0 + wc*64 + ni*16 + (lane & 15);
            float bv = bias[col];
            #pragma unroll
            for (int rg = 0; rg < 4; ++rg) {
                int row = m0 + wr*64 + mi*16 + (lane >> 4) * 4 + rg;
                float v = acc[mi][ni][rg] + bv;
                if (col == 0) v = -INFINITY;
                out[(size_t)row * OUTW + col] = v;
            }
        }
    }
}

// ---------- 3b. copy einsums via split-bf16 MFMA GEMM ----------
__global__ __launch_bounds__(256) void copy_gemm(const unsigned short* __restrict__ ahi_s,
                                                 const unsigned short* __restrict__ alo_s,
                                                 const unsigned short* __restrict__ ahi_t,
                                                 const unsigned short* __restrict__ alo_t,
                                                 const unsigned short* __restrict__ mt_s,
                                                 const unsigned short* __restrict__ mt_t,
                                                 const double* __restrict__ p,
                                                 float* __restrict__ out) {
    __shared__ __align__(16) unsigned short As[128 * 32];
    __shared__ __align__(16) unsigned short Bs[128 * 32];
    int tid  = threadIdx.x;
    int lane = tid & 63;
    int w    = tid >> 6;
    int wr   = w >> 1, wc = w & 1;
    int m0 = blockIdx.x * 128;          // T tile (512 -> 4)
    int n0 = blockIdx.y * 128;          // D tile (640 -> 5)
    int z  = blockIdx.z;                // 8: b*2 + sel
    int b = z >> 1, sel = z & 1;

    const unsigned short* Ahi = (sel ? ahi_t : ahi_s) + (size_t)b * Tt * Ss;
    const unsigned short* Alo = (sel ? alo_t : alo_s) + (size_t)b * Tt * Ss;
    const unsigned short* Mb  = (sel ? mt_t  : mt_s ) + (size_t)b * DP * Ss;

    f32x4 acc[4][4] = {};

    for (int kt = 0; kt < 2*Ss; kt += 32) {
        const unsigned short* Ab = (kt < Ss) ? Ahi : Alo;
        int kk = kt & (Ss - 1);
        #pragma unroll
        for (int gg = 0; gg < 2; ++gg) {
            int g = tid + gg * 256;
            int row = g >> 2, seg = g & 3;
            GLOAD_LDS16(Ab + (size_t)(m0 + row) * Ss + kk + seg * 8, &As[g * 8]);
            GLOAD_LDS16(Mb + (size_t)(n0 + row) * Ss + kk + seg * 8, &Bs[g * 8]);
        }
        __syncthreads();

        bf16x8 af[4], bfr[4];
        int r = lane & 15, k8 = (lane >> 4) * 8;
        #pragma unroll
        for (int i = 0; i < 4; ++i) {
            af[i]  = *reinterpret_cast<const bf16x8*>(&As[(wr*64 + i*16 + r) * 32 + k8]);
            bfr[i] = *reinterpret_cast<const bf16x8*>(&Bs[(wc*64 + i*16 + r) * 32 + k8]);
        }
        #pragma unroll
        for (int mi = 0; mi < 4; ++mi)
            #pragma unroll
            for (int ni = 0; ni < 4; ++ni)
                acc[mi][ni] = __builtin_amdgcn_mfma_f32_16x16x32_bf16(af[mi], bfr[ni], acc[mi][ni], 0, 0, 0);
        __syncthreads();
    }

    int outoff = Vv + sel * Dd;
    #pragma unroll
    for (int mi = 0; mi < 4; ++mi) {
        #pragma unroll
        for (int ni = 0; ni < 4; ++ni) {
            int col = n0 + wc*64 + ni*16 + (lane & 15);
            if (col < Dd) {
                #pragma unroll
                for (int rg = 0; rg < 4; ++rg) {
                    int rt = m0 + wr*64 + mi*16 + (lane >> 4) * 4 + rg;
                    int grow = b * Tt + rt;
                    float val = (float)((double)acc[mi][ni][rg] * p[grow*3 + sel]);
                    out[(size_t)grow * OUTW + outoff + col] = val;
                }
            }
        }
    }
}

// ---------- 4. per-row softmax stats + vocab argmax ----------
__global__ __launch_bounds__(256) void softmax_stats(const float* __restrict__ out,
                                                     float* __restrict__ rowmax,
                                                     float* __restrict__ rowsum,
                                                     int* __restrict__ rowidx) {
    int row = blockIdx.x, tid = threadIdx.x;
    const float* x = out + (size_t)row * OUTW;
    float m = -1e30f, s = 0.0f; int idx = 0x7fffffff;
    for (int v = tid; v < Vv; v += 256) {
        float val = x[v];
        if (val > m) {
            s = s * expf(m - val);
            m = val; idx = v;
            s += 1.0f;
        } else {
            s += expf(val - m);
        }
    }
    // wave-level merge
    for (int off = 32; off > 0; off >>= 1) {
        float m2 = __shfl_down(m, off);
        float s2 = __shfl_down(s, off);
        int   i2 = __shfl_down(idx, off);
        float nm = fmaxf(m, m2);
        s = s * expf(m - nm) + s2 * expf(m2 - nm);
        idx = (m2 > m) ? i2 : ((m2 == m && i2 < idx) ? i2 : idx);
        m = nm;
    }
    __shared__ float wm[4], wsum[4];
    __shared__ int wi[4];
    if ((tid & 63) == 0) { wm[tid>>6] = m; wsum[tid>>6] = s; wi[tid>>6] = idx; }
    __syncthreads();
    if (tid == 0) {
        float M = wm[0], S = wsum[0]; int I = wi[0];
        #pragma unroll
        for (int t = 1; t < 4; ++t) {
            float mt = wm[t], st = wsum[t];
            float nm = fmaxf(M, mt);
            S = S * expf(M - nm) + st * expf(mt - nm);
            I = (mt > M) ? wi[t] : ((mt == M && wi[t] < I) ? wi[t] : I);
            M = nm;
        }
        rowmax[row] = M; rowsum[row] = S; rowidx[row] = I;
    }
}

// ---------- 5. in-place vocab prob write ----------
__global__ __launch_bounds__(256) void vocab_write(float* __restrict__ out,
                                                   const float* __restrict__ rowmax,
                                                   const float* __restrict__ rowsum,
                                                   const double* __restrict__ p) {
    int row = blockIdx.y;
    int v = blockIdx.x * 256 + threadIdx.x;
    float* xr = out + (size_t)row * OUTW;
    float m = rowmax[row];
    float scale = (float)(p[row*3 + 2]) / rowsum[row];
    float val = (v == 0) ? 0.0f : expf(xr[v] - m) * scale;
    xr[v] = val;
}

// ---------- 7. predictions with exact f64 rerank ----------
__global__ __launch_bounds__(256) void pred_kernel(const float* __restrict__ out,
                                                   const int* __restrict__ rowidx,
                                                   const float* __restrict__ sattn,
                                                   const int* __restrict__ smap,
                                                   const float* __restrict__ tattn,
                                                   const int* __restrict__ tmap,
                                                   const double* __restrict__ p,
                                                   float* __restrict__ preds) {
    int row = blockIdx.x, tid = threadIdx.x;
    int b = row >> 9, t = row & (Tt - 1);
    const float* xr = out + (size_t)row * OUTW;

    __shared__ float sMa;
    __shared__ int cnt;
    __shared__ int cand[32];
    __shared__ double red[256];
    __shared__ float wm[4];

    if (tid == 0) cnt = 0;

    // phase 1: approx max over copy region
    float m = -1.0f;
    for (int d = tid; d < 2*Dd; d += 256) {
        if (d == Dd) continue;
        m = fmaxf(m, xr[Vv + d]);
    }
    for (int off = 32; off > 0; off >>= 1) m = fmaxf(m, __shfl_down(m, off));
    if ((tid & 63) == 0) wm[tid >> 6] = m;
    __syncthreads();
    if (tid == 0) sMa = fmaxf(fmaxf(wm[0], wm[1]), fmaxf(wm[2], wm[3]));
    __syncthreads();

    // phase 2: collect candidates within 0.05 of approx max
    float thr = sMa - 0.05f;
    for (int d = tid; d < 2*Dd; d += 256) {
        if (d == Dd) continue;
        if (xr[Vv + d] >= thr) {
            int pos = atomicAdd(&cnt, 1);
            if (pos < 32) cand[pos] = d;
        }
    }
    __syncthreads();
    int nc = min(cnt, 32);

    // phase 3: exact f64 recompute of candidates
    __shared__ double bestV_s;
    __shared__ int bestI_s;
    if (tid == 0) { bestV_s = -1.0; bestI_s = 0x7fffffff; }
    __syncthreads();
    for (int c = 0; c < nc; ++c) {
        int d = cand[c];
        int reg = (d >= Dd) ? 1 : 0;
        int dc = d - reg * Dd;
        const float* attn = reg ? tattn : sattn;
        const int*   map  = reg ? tmap  : smap;
        const float* arow = attn + ((size_t)b * Tt + t) * Ss;
        const int*   mb   = map + (size_t)b * Ss * Dd + dc;
        double partial = 0.0;
        for (int s = tid; s < Ss; s += 256)
            partial += (double)arow[s] * (double)mb[(size_t)s * Dd];
        red[tid] = partial;
        __syncthreads();
        for (int off = 128; off > 0; off >>= 1) {
            if (tid < off) red[tid] += red[tid + off];
            __syncthreads();
        }
        if (tid == 0) {
            double val = red[0] * p[row*3 + reg];
            int gi = Vv + d;
            if (val > bestV_s || (val == bestV_s && gi < bestI_s)) { bestV_s = val; bestI_s = gi; }
        }
        __syncthreads();
    }

    if (tid == 0) {
        int I = rowidx[row];
        double V = (double)xr[I];
        double bV = bestV_s; int bI = bestI_s;
        if (nc > 0 && (bV > V || (bV == V && bI < I))) { V = bV; I = bI; }
        preds[row] = (float)I;
    }
}

// ---------- launch ----------
extern "C" void kernel_launch(void* const* d_in, const int* in_sizes, int n_in,
                              void* d_out, int out_size, void* d_ws, size_t ws_size,
                              hipStream_t stream) {
    const float* hiddens  = (const float*)d_in[0];
    const float* src_attn = (const float*)d_in[1];
    const int*   src_map  = (const int*)  d_in[2];
    const float* tgt_attn = (const float*)d_in[3];
    const int*   tgt_map  = (const int*)  d_in[4];
    const float* W_vocab  = (const float*)d_in[5];
    const float* b_vocab  = (const float*)d_in[6];
    const float* W_switch = (const float*)d_in[7];
    const float* b_switch = (const float*)d_in[8];

    float* out = (float*)d_out;
    char* ws = (char*)d_ws;

    // region0 [0, WBF_END): hbf+wbf during scores GEMM; reused for copy buffers after
    const size_t HBF_OFF  = 0;
    const size_t WBF_OFF  = HBF_OFF + (size_t)ROWS * Hh * 2;          // 4,194,304
    const size_t WBF_END  = WBF_OFF + (size_t)Vv * Hh * 2;            // 69,730,304
    // copy-path buffers overlap region0 (used strictly after gemm_scores)
    const size_t AHI_S_OFF = 0;
    const size_t ALO_S_OFF = AHI_S_OFF + (size_t)Bb*Tt*Ss*2;          // 2,097,152
    const size_t AHI_T_OFF = ALO_S_OFF + (size_t)Bb*Tt*Ss*2;
    const size_t ALO_T_OFF = AHI_T_OFF + (size_t)Bb*Tt*Ss*2;
    const size_t MT_S_OFF  = ALO_T_OFF + (size_t)Bb*Tt*Ss*2;          // 8,388,608
    const size_t MT_T_OFF  = MT_S_OFF + (size_t)Bb*DP*Ss*2;           // 11,010,048
    // persistent small buffers after region0
    const size_t P_OFF    = WBF_END;
    const size_t RMAX_OFF = P_OFF + (size_t)ROWS * 3 * 8;
    const size_t RSUM_OFF = RMAX_OFF + (size_t)ROWS * 4;
    const size_t RIDX_OFF = RSUM_OFF + (size_t)ROWS * 4;

    unsigned short* hbf   = (unsigned short*)(ws + HBF_OFF);
    unsigned short* wbf   = (unsigned short*)(ws + WBF_OFF);
    unsigned short* ahi_s = (unsigned short*)(ws + AHI_S_OFF);
    unsigned short* alo_s = (unsigned short*)(ws + ALO_S_OFF);
    unsigned short* ahi_t = (unsigned short*)(ws + AHI_T_OFF);
    unsigned short* alo_t = (unsigned short*)(ws + ALO_T_OFF);
    unsigned short* mt_s  = (unsigned short*)(ws + MT_S_OFF);
    unsigned short* mt_t  = (unsigned short*)(ws + MT_T_OFF);
    double* pws           = (double*)(ws + P_OFF);
    float* rowmax         = (float*)(ws + RMAX_OFF);
    float* rowsum         = (float*)(ws + RSUM_OFF);
    int*   rowidx         = (int*)(ws + RIDX_OFF);

    float* preds = out + (size_t)ROWS * OUTW;

    // 1. bf16 conversions for vocab GEMM
    f32_to_bf16_kernel<<<(ROWS*Hh)/1024, 256, 0, stream>>>(hiddens, hbf, (size_t)ROWS*Hh);
    f32_to_bf16_kernel<<<((size_t)Vv*Hh)/1024, 256, 0, stream>>>(W_vocab, wbf, (size_t)Vv*Hh);

    // 2. switch softmax (f64)
    switch_kernel<<<ROWS, 64, 0, stream>>>(hiddens, W_switch, b_switch, pws);

    // 3. vocab GEMM -> raw scores into out vocab slice
    dim3 gg(ROWS/128, Vv/128);
    gemm_scores<<<gg, 256, 0, stream>>>(hbf, wbf, b_vocab, out);

    // 4. copy-path prep (reuses region0 — must be after gemm_scores)
    size_t na = (size_t)Bb * Tt * Ss;
    split_attn_kernel<<<na/1024, 256, 0, stream>>>(src_attn, ahi_s, alo_s, na);
    split_attn_kernel<<<na/1024, 256, 0, stream>>>(tgt_attn, ahi_t, alo_t, na);
    map_transpose<<<dim3(DP/32, Ss/32, Bb*2), 256, 0, stream>>>(src_map, tgt_map, mt_s, mt_t);

    // 5. softmax stats + vocab prob write
    softmax_stats<<<ROWS, 256, 0, stream>>>(out, rowmax, rowsum, rowidx);
    vocab_write<<<dim3(Vv/256, ROWS), 256, 0, stream>>>(out, rowmax, rowsum, pws);

    // 6. copy einsums via MFMA
    copy_gemm<<<dim3(Tt/128, DP/128, Bb*2), 256, 0, stream>>>(ahi_s, alo_s, ahi_t, alo_t,
                                                              mt_s, mt_t, pws, out);

    // 7. predictions (exact f64 rerank of copy candidates)
    pred_kernel<<<ROWS, 256, 0, stream>>>(out, rowidx, src_attn, src_map,
                                          tgt_attn, tgt_map, pws, preds);
}